// Round 1
// baseline (1366.139 us; speedup 1.0000x reference)
//
#include <hip/hip_runtime.h>
#include <hip/hip_bf16.h>

#define N_NODES 100000
#define N_EDGES 1600000
#define HDIM    128
#define NGRAPH  1000
#define NCLASS  10
#define BN_EPS  1e-5f

// ---------- bf16 helpers (manual, RNE; avoids API version differences) ----------
__device__ __forceinline__ float bf2f(ushort u) {
    union { unsigned int i; float f; } v; v.i = ((unsigned int)u) << 16; return v.f;
}
__device__ __forceinline__ ushort f2bf(float f) {
    union { float f; unsigned int i; } v; v.f = f;
    unsigned int i = v.i;
    unsigned int r = i + 0x7fffu + ((i >> 16) & 1u);   // round-to-nearest-even
    return (ushort)(r >> 16);
}

// ---------- 1. indegree histogram ----------
__global__ __launch_bounds__(256)
void count_deg(const int* __restrict__ dst, int* __restrict__ indeg) {
    int i = blockIdx.x * blockDim.x + threadIdx.x;
    int stride = gridDim.x * blockDim.x;
    for (int e = i; e < N_EDGES; e += stride)
        atomicAdd(&indeg[dst[e]], 1);
}

// ---------- 2. exclusive scan of indegree (single block), also dinv & cursor ----------
__global__ __launch_bounds__(1024)
void scan_deg(const int* __restrict__ indeg, int* __restrict__ row_start,
              int* __restrict__ cursor, float* __restrict__ dinv) {
    __shared__ int wsum[16];
    __shared__ int carry_sh;
    int t = threadIdx.x;
    int lane = t & 63, wid = t >> 6;
    if (t == 0) carry_sh = 0;
    __syncthreads();
    for (int base = 0; base < N_NODES; base += 1024) {
        int i = base + t;
        int v = (i < N_NODES) ? indeg[i] : 0;
        int x = v;
        #pragma unroll
        for (int off = 1; off < 64; off <<= 1) {
            int y = __shfl_up(x, off, 64);
            if (lane >= off) x += y;
        }
        if (lane == 63) wsum[wid] = x;
        __syncthreads();
        if (t == 0) {
            int s = 0;
            #pragma unroll
            for (int w = 0; w < 16; w++) { int tmp = wsum[w]; wsum[w] = s; s += tmp; }
        }
        __syncthreads();
        int excl = carry_sh + wsum[wid] + (x - v);
        if (i < N_NODES) {
            row_start[i] = excl;
            cursor[i]    = excl;
            dinv[i]      = rsqrtf(1.0f + (float)v);
        }
        __syncthreads();
        if (t == 1023) carry_sh = excl + v;
        __syncthreads();
    }
    if (t == 0) row_start[N_NODES] = N_EDGES;
}

// ---------- 3. CSR fill (src ids bucketed by dst) ----------
__global__ __launch_bounds__(256)
void fill_csr(const int* __restrict__ src, const int* __restrict__ dst,
              int* __restrict__ cursor, int* __restrict__ csr_src) {
    int i = blockIdx.x * blockDim.x + threadIdx.x;
    int stride = gridDim.x * blockDim.x;
    for (int e = i; e < N_EDGES; e += stride) {
        int d = dst[e];
        int pos = atomicAdd(&cursor[d], 1);
        csr_src[pos] = src[e];
    }
}

// ---------- 4. GEMM: hw = f(in) @ W, f = BN+ReLU (or identity), out bf16 ----------
// block = 256 threads, 32 rows/block. LDS: xs fp32 [32][136], wt bf16 [128][128].
__global__ __launch_bounds__(256)
void gemm_bn_relu(const float* __restrict__ in, const float* __restrict__ W,
                  const float* __restrict__ bnp, ushort* __restrict__ out) {
    __shared__ float  xs[32][136];
    __shared__ ushort wt[128 * 128];
    int t = threadIdx.x;
    size_t rowbase = (size_t)blockIdx.x * 32;

    // stage W -> LDS as bf16 (16384 elems; 4096 float4 loads)
    {
        const float4* Wv = (const float4*)W;
        #pragma unroll
        for (int i = 0; i < 16; i++) {
            int idx = t + i * 256;
            float4 w4 = Wv[idx];
            ushort4 pk;
            pk.x = f2bf(w4.x); pk.y = f2bf(w4.y); pk.z = f2bf(w4.z); pk.w = f2bf(w4.w);
            *(ushort4*)&wt[idx * 4] = pk;
        }
    }
    // stage x tile -> LDS with fused BN+ReLU (1024 float4 = 32x128 floats)
    {
        const float4* inv4 = (const float4*)(in + rowbase * HDIM);
        #pragma unroll
        for (int i = 0; i < 4; i++) {
            int idx = t + i * 256;
            float4 v = inv4[idx];
            int r  = idx >> 5;          // 32 float4 per row
            int kc = (idx & 31) * 4;
            if (bnp != nullptr) {
                float4 sc = *(const float4*)&bnp[kc];
                float4 sh = *(const float4*)&bnp[128 + kc];
                v.x = fmaxf(0.f, fmaf(v.x, sc.x, sh.x));
                v.y = fmaxf(0.f, fmaf(v.y, sc.y, sh.y));
                v.z = fmaxf(0.f, fmaf(v.z, sc.z, sh.z));
                v.w = fmaxf(0.f, fmaf(v.w, sc.w, sh.w));
            }
            *(float4*)&xs[r][kc] = v;
        }
    }
    __syncthreads();

    int c0 = (t & 31) * 4;   // 32 col-groups x 4 cols
    int r0 = (t >> 5) * 4;   // 8 row-groups x 4 rows
    float acc[4][4] = {};
    #pragma unroll
    for (int kc = 0; kc < 128; kc += 4) {
        float a[4][4];
        *(float4*)&a[0][0] = *(const float4*)&xs[r0 + 0][kc];
        *(float4*)&a[1][0] = *(const float4*)&xs[r0 + 1][kc];
        *(float4*)&a[2][0] = *(const float4*)&xs[r0 + 2][kc];
        *(float4*)&a[3][0] = *(const float4*)&xs[r0 + 3][kc];
        #pragma unroll
        for (int kk = 0; kk < 4; kk++) {
            ushort4 wv = *(const ushort4*)&wt[(kc + kk) * 128 + c0];
            float w0 = bf2f(wv.x), w1 = bf2f(wv.y), w2 = bf2f(wv.z), w3 = bf2f(wv.w);
            #pragma unroll
            for (int i = 0; i < 4; i++) {
                acc[i][0] += a[i][kk] * w0;
                acc[i][1] += a[i][kk] * w1;
                acc[i][2] += a[i][kk] * w2;
                acc[i][3] += a[i][kk] * w3;
            }
        }
    }
    #pragma unroll
    for (int i = 0; i < 4; i++) {
        ushort4 o;
        o.x = f2bf(acc[i][0]); o.y = f2bf(acc[i][1]);
        o.z = f2bf(acc[i][2]); o.w = f2bf(acc[i][3]);
        *(ushort4*)&out[(rowbase + r0 + i) * HDIM + c0] = o;
    }
}

// ---------- 5. gather aggregation: agg[n] = dinv[n]*(sum_e dinv[s]*hw[s] + dinv[n]*hw[n]) + b ----------
// one wave per node; lane handles features {2l, 2l+1}. BN stats fused (fp32).
__global__ __launch_bounds__(256)
void gather_agg(const ushort* __restrict__ hw, const int* __restrict__ row_start,
                const int* __restrict__ csr_src, const float* __restrict__ dinv,
                const float* __restrict__ bias, float* __restrict__ aggout,
                float* __restrict__ S1, float* __restrict__ S2) {
    __shared__ float s_sum[128];
    __shared__ float s_sq[128];
    int t = threadIdx.x;
    if (t < 128) { s_sum[t] = 0.f; s_sq[t] = 0.f; }
    __syncthreads();
    int lane = t & 63;
    int wid  = t >> 6;
    int gw = blockIdx.x * 4 + wid;
    int nw = gridDim.x * 4;
    float b0 = bias[2 * lane], b1 = bias[2 * lane + 1];
    float ls0 = 0.f, ls1 = 0.f, lq0 = 0.f, lq1 = 0.f;
    for (int n = gw; n < N_NODES; n += nw) {
        int jb = row_start[n], je = row_start[n + 1];
        float acc0 = 0.f, acc1 = 0.f;
        for (int j = jb; j < je; j++) {
            int s = csr_src[j];              // wave-uniform -> scalar load
            float d = dinv[s];
            unsigned int pk = *(const unsigned int*)&hw[(size_t)s * HDIM + 2 * lane];
            acc0 += d * bf2f((ushort)(pk & 0xffffu));
            acc1 += d * bf2f((ushort)(pk >> 16));
        }
        float dn = dinv[n];
        unsigned int pk = *(const unsigned int*)&hw[(size_t)n * HDIM + 2 * lane];
        acc0 += dn * bf2f((ushort)(pk & 0xffffu));
        acc1 += dn * bf2f((ushort)(pk >> 16));
        acc0 = fmaf(acc0, dn, b0);
        acc1 = fmaf(acc1, dn, b1);
        *(float2*)&aggout[(size_t)n * HDIM + 2 * lane] = make_float2(acc0, acc1);
        ls0 += acc0; ls1 += acc1;
        lq0 += acc0 * acc0; lq1 += acc1 * acc1;
    }
    atomicAdd(&s_sum[2 * lane],     ls0);
    atomicAdd(&s_sum[2 * lane + 1], ls1);
    atomicAdd(&s_sq[2 * lane],      lq0);
    atomicAdd(&s_sq[2 * lane + 1],  lq1);
    __syncthreads();
    if (t < 128) { atomicAdd(&S1[t], s_sum[t]); atomicAdd(&S2[t], s_sq[t]); }
}

// ---------- 6. BN parameter prep: scale/shift per feature ----------
__global__ __launch_bounds__(128)
void bn_prep(const float* __restrict__ S1, const float* __restrict__ S2,
             const float* __restrict__ gamma, const float* __restrict__ beta,
             float* __restrict__ bnp) {
    int k = threadIdx.x;
    float mean = S1[k] * (1.0f / N_NODES);
    float var  = S2[k] * (1.0f / N_NODES) - mean * mean;
    float inv  = rsqrtf(var + BN_EPS);
    float sc   = gamma[k] * inv;
    bnp[k]        = sc;
    bnp[128 + k]  = beta[k] - mean * sc;
}

// ---------- 7. mean-pool per graph (batch sorted) with fused BN+ReLU ----------
__global__ __launch_bounds__(128)
void pool_kernel(const float* __restrict__ agg, const float* __restrict__ bnp,
                 const int* __restrict__ batch, float* __restrict__ pooled) {
    int g = blockIdx.x;
    int k = threadIdx.x;
    int lo = 0, hi = N_NODES;
    while (lo < hi) { int mid = (lo + hi) >> 1; if (batch[mid] < g) lo = mid + 1; else hi = mid; }
    int start = lo;
    hi = N_NODES;
    while (lo < hi) { int mid = (lo + hi) >> 1; if (batch[mid] < g + 1) lo = mid + 1; else hi = mid; }
    int end = lo;
    float sc = bnp[k], sh = bnp[128 + k];
    float sum = 0.f;
    for (int n = start; n < end; n++)
        sum += fmaxf(0.f, fmaf(agg[(size_t)n * HDIM + k], sc, sh));
    float cnt = (float)(end - start);
    pooled[g * HDIM + k] = sum / fmaxf(cnt, 1.0f);
}

// ---------- 8. classifier MLP ----------
__global__ __launch_bounds__(128)
void mlp_kernel(const float* __restrict__ pooled, const float* __restrict__ w1,
                const float* __restrict__ b1, const float* __restrict__ w2,
                const float* __restrict__ b2, float* __restrict__ out) {
    __shared__ float p[128];
    __shared__ float z[64];
    int g = blockIdx.x;
    int t = threadIdx.x;
    p[t] = pooled[g * HDIM + t];
    __syncthreads();
    if (t < 64) {
        float s = b1[t];
        #pragma unroll 8
        for (int k = 0; k < 128; k++) s += p[k] * w1[k * 64 + t];
        z[t] = fmaxf(0.f, s);
    }
    __syncthreads();
    if (t < NCLASS) {
        float s = b2[t];
        #pragma unroll
        for (int j = 0; j < 64; j++) s += z[j] * w2[j * NCLASS + t];
        out[g * NCLASS + t] = s;
    }
}

extern "C" void kernel_launch(void* const* d_in, const int* in_sizes, int n_in,
                              void* d_out, int out_size, void* d_ws, size_t ws_size,
                              hipStream_t stream) {
    const float* x      = (const float*)d_in[0];
    const float* conv_w = (const float*)d_in[1];
    const float* conv_b = (const float*)d_in[2];
    const float* gamma  = (const float*)d_in[3];
    const float* beta   = (const float*)d_in[4];
    const float* w1     = (const float*)d_in[5];
    const float* b1     = (const float*)d_in[6];
    const float* w2     = (const float*)d_in[7];
    const float* b2     = (const float*)d_in[8];
    const int*   ei     = (const int*)d_in[9];    // [2,E] int32 per harness convention
    const int*   batch  = (const int*)d_in[10];
    float* out = (float*)d_out;

    char* ws = (char*)d_ws;
    size_t off = 0;
    auto alloc = [&](size_t bytes) -> void* {
        off = (off + 255) & ~(size_t)255;
        void* p = ws + off;
        off += bytes;
        return p;
    };
    ushort* A        = (ushort*)alloc((size_t)N_NODES * HDIM * 2);   // hw, bf16
    float*  B        = (float*) alloc((size_t)N_NODES * HDIM * 4);   // agg, fp32
    int*    csr_src  = (int*)   alloc((size_t)N_EDGES * 4);
    int*    row_start= (int*)   alloc((size_t)(N_NODES + 1) * 4);
    int*    cursor   = (int*)   alloc((size_t)N_NODES * 4);
    int*    indeg    = (int*)   alloc((size_t)N_NODES * 4);
    float*  dinv     = (float*) alloc((size_t)N_NODES * 4);
    float*  bnstats  = (float*) alloc(3 * 256 * 4);
    float*  bnp      = (float*) alloc(3 * 256 * 4);
    float*  pooled   = (float*) alloc((size_t)NGRAPH * HDIM * 4);

    const int* srcv = ei;
    const int* dstv = ei + N_EDGES;

    hipMemsetAsync(indeg,   0, (size_t)N_NODES * 4, stream);
    hipMemsetAsync(bnstats, 0, 3 * 256 * 4, stream);

    count_deg<<<1024, 256, 0, stream>>>(dstv, indeg);
    scan_deg <<<1, 1024, 0, stream>>>(indeg, row_start, cursor, dinv);
    fill_csr <<<1024, 256, 0, stream>>>(srcv, dstv, cursor, csr_src);

    for (int l = 0; l < 3; l++) {
        const float* inl  = (l == 0) ? x : B;
        const float* bnpl = (l == 0) ? nullptr : (bnp + (l - 1) * 256);
        gemm_bn_relu<<<N_NODES / 32, 256, 0, stream>>>(inl, conv_w + l * HDIM * HDIM, bnpl, A);
        gather_agg  <<<1024, 256, 0, stream>>>(A, row_start, csr_src, dinv,
                                               conv_b + l * HDIM, B,
                                               bnstats + l * 256, bnstats + l * 256 + 128);
        bn_prep     <<<1, 128, 0, stream>>>(bnstats + l * 256, bnstats + l * 256 + 128,
                                            gamma + l * HDIM, beta + l * HDIM, bnp + l * 256);
    }
    pool_kernel<<<NGRAPH, 128, 0, stream>>>(B, bnp + 2 * 256, batch, pooled);
    mlp_kernel <<<NGRAPH, 128, 0, stream>>>(pooled, w1, b1, w2, b2, out);
}

// Round 2
// 946.562 us; speedup vs baseline: 1.4433x; 1.4433x over previous
//
#include <hip/hip_runtime.h>
#include <hip/hip_bf16.h>

#define N_NODES 100000
#define N_EDGES 1600000
#define HDIM    128
#define NGRAPH  1000
#define NCLASS  10
#define BN_EPS  1e-5f

// ---------- bf16 helpers (manual, RNE) ----------
__device__ __forceinline__ float bf2f(ushort u) {
    union { unsigned int i; float f; } v; v.i = ((unsigned int)u) << 16; return v.f;
}
__device__ __forceinline__ ushort f2bf(float f) {
    union { float f; unsigned int i; } v; v.f = f;
    unsigned int i = v.i;
    unsigned int r = i + 0x7fffu + ((i >> 16) & 1u);
    return (ushort)(r >> 16);
}

// ---------- 1. indegree histogram ----------
__global__ __launch_bounds__(256)
void count_deg(const int* __restrict__ dst, int* __restrict__ indeg) {
    int i = blockIdx.x * blockDim.x + threadIdx.x;
    int stride = gridDim.x * blockDim.x;
    for (int e = i; e < N_EDGES; e += stride)
        atomicAdd(&indeg[dst[e]], 1);
}

// ---------- 2. exclusive scan (single block), also dinv & cursor ----------
__global__ __launch_bounds__(1024)
void scan_deg(const int* __restrict__ indeg, int* __restrict__ row_start,
              int* __restrict__ cursor, float* __restrict__ dinv) {
    __shared__ int wsum[16];
    __shared__ int carry_sh;
    int t = threadIdx.x;
    int lane = t & 63, wid = t >> 6;
    if (t == 0) carry_sh = 0;
    __syncthreads();
    for (int base = 0; base < N_NODES; base += 1024) {
        int i = base + t;
        int v = (i < N_NODES) ? indeg[i] : 0;
        int x = v;
        #pragma unroll
        for (int off = 1; off < 64; off <<= 1) {
            int y = __shfl_up(x, off, 64);
            if (lane >= off) x += y;
        }
        if (lane == 63) wsum[wid] = x;
        __syncthreads();
        if (t == 0) {
            int s = 0;
            #pragma unroll
            for (int w = 0; w < 16; w++) { int tmp = wsum[w]; wsum[w] = s; s += tmp; }
        }
        __syncthreads();
        int excl = carry_sh + wsum[wid] + (x - v);
        if (i < N_NODES) {
            row_start[i] = excl;
            cursor[i]    = excl;
            dinv[i]      = rsqrtf(1.0f + (float)v);
        }
        __syncthreads();
        if (t == 1023) carry_sh = excl + v;
        __syncthreads();
    }
    if (t == 0) row_start[N_NODES] = N_EDGES;
}

// ---------- 3. CSR fill ----------
__global__ __launch_bounds__(256)
void fill_csr(const int* __restrict__ src, const int* __restrict__ dst,
              int* __restrict__ cursor, int* __restrict__ csr_src) {
    int i = blockIdx.x * blockDim.x + threadIdx.x;
    int stride = gridDim.x * blockDim.x;
    for (int e = i; e < N_EDGES; e += stride) {
        int d = dst[e];
        int pos = atomicAdd(&cursor[d], 1);
        csr_src[pos] = src[e];
    }
}

// ---------- 4. GEMM: A' = dinv * f(in) @ W  (f = BN+ReLU or identity), out bf16 ----------
__global__ __launch_bounds__(256)
void gemm_bn_relu(const float* __restrict__ in, const float* __restrict__ W,
                  const float* __restrict__ bnp, const float* __restrict__ dinv,
                  ushort* __restrict__ out) {
    __shared__ float  xs[32][136];
    __shared__ ushort wt[128 * 128];
    int t = threadIdx.x;
    size_t rowbase = (size_t)blockIdx.x * 32;

    {
        const float4* Wv = (const float4*)W;
        #pragma unroll
        for (int i = 0; i < 16; i++) {
            int idx = t + i * 256;
            float4 w4 = Wv[idx];
            ushort4 pk;
            pk.x = f2bf(w4.x); pk.y = f2bf(w4.y); pk.z = f2bf(w4.z); pk.w = f2bf(w4.w);
            *(ushort4*)&wt[idx * 4] = pk;
        }
    }
    {
        const float4* inv4 = (const float4*)(in + rowbase * HDIM);
        #pragma unroll
        for (int i = 0; i < 4; i++) {
            int idx = t + i * 256;
            float4 v = inv4[idx];
            int r  = idx >> 5;
            int kc = (idx & 31) * 4;
            if (bnp != nullptr) {
                float4 sc = *(const float4*)&bnp[kc];
                float4 sh = *(const float4*)&bnp[128 + kc];
                v.x = fmaxf(0.f, fmaf(v.x, sc.x, sh.x));
                v.y = fmaxf(0.f, fmaf(v.y, sc.y, sh.y));
                v.z = fmaxf(0.f, fmaf(v.z, sc.z, sh.z));
                v.w = fmaxf(0.f, fmaf(v.w, sc.w, sh.w));
            }
            *(float4*)&xs[r][kc] = v;
        }
    }
    __syncthreads();

    int c0 = (t & 31) * 4;
    int r0 = (t >> 5) * 4;
    float acc[4][4] = {};
    #pragma unroll
    for (int kc = 0; kc < 128; kc += 4) {
        float a[4][4];
        *(float4*)&a[0][0] = *(const float4*)&xs[r0 + 0][kc];
        *(float4*)&a[1][0] = *(const float4*)&xs[r0 + 1][kc];
        *(float4*)&a[2][0] = *(const float4*)&xs[r0 + 2][kc];
        *(float4*)&a[3][0] = *(const float4*)&xs[r0 + 3][kc];
        #pragma unroll
        for (int kk = 0; kk < 4; kk++) {
            ushort4 wv = *(const ushort4*)&wt[(kc + kk) * 128 + c0];
            float w0 = bf2f(wv.x), w1 = bf2f(wv.y), w2 = bf2f(wv.z), w3 = bf2f(wv.w);
            #pragma unroll
            for (int i = 0; i < 4; i++) {
                acc[i][0] += a[i][kk] * w0;
                acc[i][1] += a[i][kk] * w1;
                acc[i][2] += a[i][kk] * w2;
                acc[i][3] += a[i][kk] * w3;
            }
        }
    }
    // epilogue: pre-scale rows by dinv[row] so gather needs no dinv[s] load
    #pragma unroll
    for (int i = 0; i < 4; i++) {
        float dv = dinv[rowbase + r0 + i];
        ushort4 o;
        o.x = f2bf(acc[i][0] * dv); o.y = f2bf(acc[i][1] * dv);
        o.z = f2bf(acc[i][2] * dv); o.w = f2bf(acc[i][3] * dv);
        *(ushort4*)&out[(rowbase + r0 + i) * HDIM + c0] = o;
    }
}

// ---------- 5. gather: agg[n] = dinv[n]*(sum_e A'[s] + A'[n]) + b ----------
// one wave per node; lane holds features {2l,2l+1}. Edge loop unrolled x4 for MLP.
__global__ __launch_bounds__(256)
void gather_agg(const ushort* __restrict__ hw, const int* __restrict__ row_start,
                const int* __restrict__ csr_src, const float* __restrict__ dinv,
                const float* __restrict__ bias, float* __restrict__ aggout,
                float* __restrict__ S1, float* __restrict__ S2) {
    __shared__ float s_sum[128];
    __shared__ float s_sq[128];
    int t = threadIdx.x;
    if (t < 128) { s_sum[t] = 0.f; s_sq[t] = 0.f; }
    __syncthreads();
    int lane = t & 63;
    int wid  = t >> 6;
    int gw = blockIdx.x * 4 + wid;
    int nw = gridDim.x * 4;
    int fo = 2 * lane;                     // feature offset (packed pair)
    float b0 = bias[fo], b1 = bias[fo + 1];
    float ls0 = 0.f, ls1 = 0.f, lq0 = 0.f, lq1 = 0.f;
    for (int n = gw; n < N_NODES; n += nw) {
        int jb = row_start[n], je = row_start[n + 1];
        float acc0 = 0.f, acc1 = 0.f;
        int j = jb;
        for (; j + 4 <= je; j += 4) {
            int s0 = csr_src[j];
            int s1 = csr_src[j + 1];
            int s2 = csr_src[j + 2];
            int s3 = csr_src[j + 3];
            unsigned int p0 = *(const unsigned int*)&hw[(size_t)s0 * HDIM + fo];
            unsigned int p1 = *(const unsigned int*)&hw[(size_t)s1 * HDIM + fo];
            unsigned int p2 = *(const unsigned int*)&hw[(size_t)s2 * HDIM + fo];
            unsigned int p3 = *(const unsigned int*)&hw[(size_t)s3 * HDIM + fo];
            acc0 += bf2f((ushort)(p0 & 0xffffu)) + bf2f((ushort)(p1 & 0xffffu))
                  + bf2f((ushort)(p2 & 0xffffu)) + bf2f((ushort)(p3 & 0xffffu));
            acc1 += bf2f((ushort)(p0 >> 16)) + bf2f((ushort)(p1 >> 16))
                  + bf2f((ushort)(p2 >> 16)) + bf2f((ushort)(p3 >> 16));
        }
        for (; j < je; j++) {
            int s = csr_src[j];
            unsigned int pk = *(const unsigned int*)&hw[(size_t)s * HDIM + fo];
            acc0 += bf2f((ushort)(pk & 0xffffu));
            acc1 += bf2f((ushort)(pk >> 16));
        }
        // self-loop (row already pre-scaled by dinv[n])
        unsigned int pk = *(const unsigned int*)&hw[(size_t)n * HDIM + fo];
        acc0 += bf2f((ushort)(pk & 0xffffu));
        acc1 += bf2f((ushort)(pk >> 16));
        float dn = dinv[n];
        acc0 = fmaf(acc0, dn, b0);
        acc1 = fmaf(acc1, dn, b1);
        *(float2*)&aggout[(size_t)n * HDIM + fo] = make_float2(acc0, acc1);
        ls0 += acc0; ls1 += acc1;
        lq0 += acc0 * acc0; lq1 += acc1 * acc1;
    }
    atomicAdd(&s_sum[fo],     ls0);
    atomicAdd(&s_sum[fo + 1], ls1);
    atomicAdd(&s_sq[fo],      lq0);
    atomicAdd(&s_sq[fo + 1],  lq1);
    __syncthreads();
    if (t < 128) { atomicAdd(&S1[t], s_sum[t]); atomicAdd(&S2[t], s_sq[t]); }
}

// ---------- 6. BN parameter prep ----------
__global__ __launch_bounds__(128)
void bn_prep(const float* __restrict__ S1, const float* __restrict__ S2,
             const float* __restrict__ gamma, const float* __restrict__ beta,
             float* __restrict__ bnp) {
    int k = threadIdx.x;
    float mean = S1[k] * (1.0f / N_NODES);
    float var  = S2[k] * (1.0f / N_NODES) - mean * mean;
    float inv  = rsqrtf(var + BN_EPS);
    float sc   = gamma[k] * inv;
    bnp[k]        = sc;
    bnp[128 + k]  = beta[k] - mean * sc;
}

// ---------- 7. mean-pool per graph with fused BN+ReLU ----------
__global__ __launch_bounds__(128)
void pool_kernel(const float* __restrict__ agg, const float* __restrict__ bnp,
                 const int* __restrict__ batch, float* __restrict__ pooled) {
    int g = blockIdx.x;
    int k = threadIdx.x;
    int lo = 0, hi = N_NODES;
    while (lo < hi) { int mid = (lo + hi) >> 1; if (batch[mid] < g) lo = mid + 1; else hi = mid; }
    int start = lo;
    hi = N_NODES;
    while (lo < hi) { int mid = (lo + hi) >> 1; if (batch[mid] < g + 1) lo = mid + 1; else hi = mid; }
    int end = lo;
    float sc = bnp[k], sh = bnp[128 + k];
    float sum = 0.f;
    for (int n = start; n < end; n++)
        sum += fmaxf(0.f, fmaf(agg[(size_t)n * HDIM + k], sc, sh));
    float cnt = (float)(end - start);
    pooled[g * HDIM + k] = sum / fmaxf(cnt, 1.0f);
}

// ---------- 8. classifier MLP ----------
__global__ __launch_bounds__(128)
void mlp_kernel(const float* __restrict__ pooled, const float* __restrict__ w1,
                const float* __restrict__ b1, const float* __restrict__ w2,
                const float* __restrict__ b2, float* __restrict__ out) {
    __shared__ float p[128];
    __shared__ float z[64];
    int g = blockIdx.x;
    int t = threadIdx.x;
    p[t] = pooled[g * HDIM + t];
    __syncthreads();
    if (t < 64) {
        float s = b1[t];
        #pragma unroll 8
        for (int k = 0; k < 128; k++) s += p[k] * w1[k * 64 + t];
        z[t] = fmaxf(0.f, s);
    }
    __syncthreads();
    if (t < NCLASS) {
        float s = b2[t];
        #pragma unroll
        for (int j = 0; j < 64; j++) s += z[j] * w2[j * NCLASS + t];
        out[g * NCLASS + t] = s;
    }
}

extern "C" void kernel_launch(void* const* d_in, const int* in_sizes, int n_in,
                              void* d_out, int out_size, void* d_ws, size_t ws_size,
                              hipStream_t stream) {
    const float* x      = (const float*)d_in[0];
    const float* conv_w = (const float*)d_in[1];
    const float* conv_b = (const float*)d_in[2];
    const float* gamma  = (const float*)d_in[3];
    const float* beta   = (const float*)d_in[4];
    const float* w1     = (const float*)d_in[5];
    const float* b1     = (const float*)d_in[6];
    const float* w2     = (const float*)d_in[7];
    const float* b2     = (const float*)d_in[8];
    const int*   ei     = (const int*)d_in[9];
    const int*   batch  = (const int*)d_in[10];
    float* out = (float*)d_out;

    char* ws = (char*)d_ws;
    size_t off = 0;
    auto alloc = [&](size_t bytes) -> void* {
        off = (off + 255) & ~(size_t)255;
        void* p = ws + off;
        off += bytes;
        return p;
    };
    ushort* A        = (ushort*)alloc((size_t)N_NODES * HDIM * 2);
    float*  B        = (float*) alloc((size_t)N_NODES * HDIM * 4);
    int*    csr_src  = (int*)   alloc((size_t)N_EDGES * 4);
    int*    row_start= (int*)   alloc((size_t)(N_NODES + 1) * 4);
    int*    cursor   = (int*)   alloc((size_t)N_NODES * 4);
    int*    indeg    = (int*)   alloc((size_t)N_NODES * 4);
    float*  dinv     = (float*) alloc((size_t)N_NODES * 4);
    float*  bnstats  = (float*) alloc(3 * 256 * 4);
    float*  bnp      = (float*) alloc(3 * 256 * 4);
    float*  pooled   = (float*) alloc((size_t)NGRAPH * HDIM * 4);

    const int* srcv = ei;
    const int* dstv = ei + N_EDGES;

    hipMemsetAsync(indeg,   0, (size_t)N_NODES * 4, stream);
    hipMemsetAsync(bnstats, 0, 3 * 256 * 4, stream);

    count_deg<<<1024, 256, 0, stream>>>(dstv, indeg);
    scan_deg <<<1, 1024, 0, stream>>>(indeg, row_start, cursor, dinv);
    fill_csr <<<1024, 256, 0, stream>>>(srcv, dstv, cursor, csr_src);

    for (int l = 0; l < 3; l++) {
        const float* inl  = (l == 0) ? x : B;
        const float* bnpl = (l == 0) ? nullptr : (bnp + (l - 1) * 256);
        gemm_bn_relu<<<N_NODES / 32, 256, 0, stream>>>(inl, conv_w + l * HDIM * HDIM, bnpl, dinv, A);
        gather_agg  <<<2048, 256, 0, stream>>>(A, row_start, csr_src, dinv,
                                               conv_b + l * HDIM, B,
                                               bnstats + l * 256, bnstats + l * 256 + 128);
        bn_prep     <<<1, 128, 0, stream>>>(bnstats + l * 256, bnstats + l * 256 + 128,
                                            gamma + l * HDIM, beta + l * HDIM, bnp + l * 256);
    }
    pool_kernel<<<NGRAPH, 128, 0, stream>>>(B, bnp + 2 * 256, batch, pooled);
    mlp_kernel <<<NGRAPH, 128, 0, stream>>>(pooled, w1, b1, w2, b2, out);
}

// Round 3
// 757.501 us; speedup vs baseline: 1.8035x; 1.2496x over previous
//
#include <hip/hip_runtime.h>
#include <hip/hip_bf16.h>

#define N_NODES 100000
#define N_EDGES 1600000
#define HDIM    128
#define NGRAPH  1000
#define NCLASS  10
#define BN_EPS  1e-5f

#define NBUCKET 391          // ceil(N_NODES / 256)
#define TILE3   16384        // edges per scatter block

// ---------- bf16 helpers (manual, RNE) ----------
__device__ __forceinline__ float bf2f(ushort u) {
    union { unsigned int i; float f; } v; v.i = ((unsigned int)u) << 16; return v.f;
}
__device__ __forceinline__ ushort f2bf(float f) {
    union { float f; unsigned int i; } v; v.f = f;
    unsigned int i = v.i;
    unsigned int r = i + 0x7fffu + ((i >> 16) & 1u);
    return (ushort)(r >> 16);
}

// ---------- 1a. bucket histogram (bucket = dst >> 8) ----------
__global__ __launch_bounds__(256)
void bucket_hist(const int* __restrict__ dst, int* __restrict__ gcnt) {
    __shared__ int h[NBUCKET];
    int t = threadIdx.x;
    for (int i = t; i < NBUCKET; i += 256) h[i] = 0;
    __syncthreads();
    int i0 = blockIdx.x * blockDim.x + t;
    int stride = gridDim.x * blockDim.x;
    for (int e = i0; e < N_EDGES; e += stride)
        atomicAdd(&h[dst[e] >> 8], 1);
    __syncthreads();
    for (int i = t; i < NBUCKET; i += 256)
        if (h[i]) atomicAdd(&gcnt[i], h[i]);
}

// ---------- 1b. bucket scan (391 elems, serial) ----------
__global__ void bucket_scan(const int* __restrict__ gcnt, int* __restrict__ bucket_base,
                            int* __restrict__ bucket_cursor, int* __restrict__ row_start) {
    if (threadIdx.x == 0) {
        int s = 0;
        for (int i = 0; i < NBUCKET; i++) {
            bucket_base[i] = s;
            bucket_cursor[i] = s;
            s += gcnt[i];
        }
        bucket_base[NBUCKET] = s;
        row_start[N_NODES] = N_EDGES;
    }
}

// ---------- 1c. tile-local scatter of packed (src | local<<24) into bucket runs ----------
__global__ __launch_bounds__(256)
void scatter_pairs(const int* __restrict__ src, const int* __restrict__ dst,
                   int* __restrict__ bucket_cursor, unsigned int* __restrict__ pairs) {
    __shared__ int lhist[NBUCKET];
    __shared__ int lbase[NBUCKET];
    __shared__ int lcur[NBUCKET];
    int t = threadIdx.x;
    long tile0 = (long)blockIdx.x * TILE3;
    for (int i = t; i < NBUCKET; i += 256) { lhist[i] = 0; lcur[i] = 0; }
    __syncthreads();
    #pragma unroll 4
    for (int i = 0; i < TILE3 / 256; i++) {
        long e = tile0 + t + i * 256;
        if (e < N_EDGES) atomicAdd(&lhist[dst[e] >> 8], 1);
    }
    __syncthreads();
    for (int i = t; i < NBUCKET; i += 256)
        if (lhist[i] > 0) lbase[i] = atomicAdd(&bucket_cursor[i], lhist[i]);
    __syncthreads();
    #pragma unroll 4
    for (int i = 0; i < TILE3 / 256; i++) {
        long e = tile0 + t + i * 256;
        if (e < N_EDGES) {
            int d = dst[e];
            int bkt = d >> 8;
            int p = atomicAdd(&lcur[bkt], 1);
            pairs[lbase[bkt] + p] = (unsigned int)src[e] | ((unsigned int)(d & 255) << 24);
        }
    }
}

// ---------- 1d. per-bucket CSR build (one block per bucket) ----------
__global__ __launch_bounds__(256)
void build_csr(const unsigned int* __restrict__ pairs, const int* __restrict__ bucket_base,
               int* __restrict__ row_start, int* __restrict__ csr_src, float* __restrict__ dinv) {
    __shared__ int hist[256];
    __shared__ int cur[256];
    __shared__ int wsum[4];
    int b = blockIdx.x;
    int t = threadIdx.x;
    int beg = bucket_base[b], end = bucket_base[b + 1];
    hist[t] = 0;
    __syncthreads();
    for (int e = beg + t; e < end; e += 256)
        atomicAdd(&hist[pairs[e] >> 24], 1);
    __syncthreads();
    int v = hist[t];
    int lane = t & 63, wid = t >> 6;
    int x = v;
    #pragma unroll
    for (int off = 1; off < 64; off <<= 1) {
        int y = __shfl_up(x, off, 64);
        if (lane >= off) x += y;
    }
    if (lane == 63) wsum[wid] = x;
    __syncthreads();
    if (t == 0) {
        int s = 0;
        #pragma unroll
        for (int w = 0; w < 4; w++) { int tmp = wsum[w]; wsum[w] = s; s += tmp; }
    }
    __syncthreads();
    int excl = wsum[wid] + (x - v);
    cur[t] = excl;
    int node = b * 256 + t;
    if (node < N_NODES) {
        row_start[node] = beg + excl;
        dinv[node] = rsqrtf(1.0f + (float)v);
    }
    __syncthreads();
    for (int e = beg + t; e < end; e += 256) {
        unsigned int pk = pairs[e];
        int ln = pk >> 24;
        int sp = atomicAdd(&cur[ln], 1);
        csr_src[beg + sp] = (int)(pk & 0xFFFFFFu);
    }
}

// ---------- 2. GEMM: A' = dinv * f(in) @ W  (f = BN+ReLU or identity), out bf16 ----------
__global__ __launch_bounds__(256)
void gemm_bn_relu(const float* __restrict__ in, const float* __restrict__ W,
                  const float* __restrict__ bnp, const float* __restrict__ dinv,
                  ushort* __restrict__ out) {
    __shared__ float  xs[32][136];
    __shared__ ushort wt[128 * 128];
    int t = threadIdx.x;
    size_t rowbase = (size_t)blockIdx.x * 32;

    {
        const float4* Wv = (const float4*)W;
        #pragma unroll
        for (int i = 0; i < 16; i++) {
            int idx = t + i * 256;
            float4 w4 = Wv[idx];
            ushort4 pk;
            pk.x = f2bf(w4.x); pk.y = f2bf(w4.y); pk.z = f2bf(w4.z); pk.w = f2bf(w4.w);
            *(ushort4*)&wt[idx * 4] = pk;
        }
    }
    {
        const float4* inv4 = (const float4*)(in + rowbase * HDIM);
        #pragma unroll
        for (int i = 0; i < 4; i++) {
            int idx = t + i * 256;
            float4 v = inv4[idx];
            int r  = idx >> 5;
            int kc = (idx & 31) * 4;
            if (bnp != nullptr) {
                float4 sc = *(const float4*)&bnp[kc];
                float4 sh = *(const float4*)&bnp[128 + kc];
                v.x = fmaxf(0.f, fmaf(v.x, sc.x, sh.x));
                v.y = fmaxf(0.f, fmaf(v.y, sc.y, sh.y));
                v.z = fmaxf(0.f, fmaf(v.z, sc.z, sh.z));
                v.w = fmaxf(0.f, fmaf(v.w, sc.w, sh.w));
            }
            *(float4*)&xs[r][kc] = v;
        }
    }
    __syncthreads();

    int c0 = (t & 31) * 4;
    int r0 = (t >> 5) * 4;
    float acc[4][4] = {};
    #pragma unroll
    for (int kc = 0; kc < 128; kc += 4) {
        float a[4][4];
        *(float4*)&a[0][0] = *(const float4*)&xs[r0 + 0][kc];
        *(float4*)&a[1][0] = *(const float4*)&xs[r0 + 1][kc];
        *(float4*)&a[2][0] = *(const float4*)&xs[r0 + 2][kc];
        *(float4*)&a[3][0] = *(const float4*)&xs[r0 + 3][kc];
        #pragma unroll
        for (int kk = 0; kk < 4; kk++) {
            ushort4 wv = *(const ushort4*)&wt[(kc + kk) * 128 + c0];
            float w0 = bf2f(wv.x), w1 = bf2f(wv.y), w2 = bf2f(wv.z), w3 = bf2f(wv.w);
            #pragma unroll
            for (int i = 0; i < 4; i++) {
                acc[i][0] += a[i][kk] * w0;
                acc[i][1] += a[i][kk] * w1;
                acc[i][2] += a[i][kk] * w2;
                acc[i][3] += a[i][kk] * w3;
            }
        }
    }
    #pragma unroll
    for (int i = 0; i < 4; i++) {
        float dv = dinv[rowbase + r0 + i];
        ushort4 o;
        o.x = f2bf(acc[i][0] * dv); o.y = f2bf(acc[i][1] * dv);
        o.z = f2bf(acc[i][2] * dv); o.w = f2bf(acc[i][3] * dv);
        *(ushort4*)&out[(rowbase + r0 + i) * HDIM + c0] = o;
    }
}

// ---------- 3. gather: agg[n] = dinv[n]*(sum_e A'[s] + A'[n]) + b ----------
__global__ __launch_bounds__(256)
void gather_agg(const ushort* __restrict__ hw, const int* __restrict__ row_start,
                const int* __restrict__ csr_src, const float* __restrict__ dinv,
                const float* __restrict__ bias, float* __restrict__ aggout,
                float* __restrict__ S1, float* __restrict__ S2) {
    __shared__ float s_sum[128];
    __shared__ float s_sq[128];
    int t = threadIdx.x;
    if (t < 128) { s_sum[t] = 0.f; s_sq[t] = 0.f; }
    __syncthreads();
    int lane = t & 63;
    int wid  = t >> 6;
    int gw = blockIdx.x * 4 + wid;
    int nw = gridDim.x * 4;
    int fo = 2 * lane;
    float b0 = bias[fo], b1 = bias[fo + 1];
    float ls0 = 0.f, ls1 = 0.f, lq0 = 0.f, lq1 = 0.f;
    for (int n = gw; n < N_NODES; n += nw) {
        int jb = row_start[n], je = row_start[n + 1];
        float acc0 = 0.f, acc1 = 0.f;
        int j = jb;
        for (; j + 8 <= je; j += 8) {
            int s0 = csr_src[j];     int s1 = csr_src[j + 1];
            int s2 = csr_src[j + 2]; int s3 = csr_src[j + 3];
            int s4 = csr_src[j + 4]; int s5 = csr_src[j + 5];
            int s6 = csr_src[j + 6]; int s7 = csr_src[j + 7];
            unsigned int p0 = *(const unsigned int*)&hw[(size_t)s0 * HDIM + fo];
            unsigned int p1 = *(const unsigned int*)&hw[(size_t)s1 * HDIM + fo];
            unsigned int p2 = *(const unsigned int*)&hw[(size_t)s2 * HDIM + fo];
            unsigned int p3 = *(const unsigned int*)&hw[(size_t)s3 * HDIM + fo];
            unsigned int p4 = *(const unsigned int*)&hw[(size_t)s4 * HDIM + fo];
            unsigned int p5 = *(const unsigned int*)&hw[(size_t)s5 * HDIM + fo];
            unsigned int p6 = *(const unsigned int*)&hw[(size_t)s6 * HDIM + fo];
            unsigned int p7 = *(const unsigned int*)&hw[(size_t)s7 * HDIM + fo];
            acc0 += bf2f((ushort)(p0 & 0xffffu)) + bf2f((ushort)(p1 & 0xffffu))
                  + bf2f((ushort)(p2 & 0xffffu)) + bf2f((ushort)(p3 & 0xffffu))
                  + bf2f((ushort)(p4 & 0xffffu)) + bf2f((ushort)(p5 & 0xffffu))
                  + bf2f((ushort)(p6 & 0xffffu)) + bf2f((ushort)(p7 & 0xffffu));
            acc1 += bf2f((ushort)(p0 >> 16)) + bf2f((ushort)(p1 >> 16))
                  + bf2f((ushort)(p2 >> 16)) + bf2f((ushort)(p3 >> 16))
                  + bf2f((ushort)(p4 >> 16)) + bf2f((ushort)(p5 >> 16))
                  + bf2f((ushort)(p6 >> 16)) + bf2f((ushort)(p7 >> 16));
        }
        for (; j < je; j++) {
            int s = csr_src[j];
            unsigned int pk = *(const unsigned int*)&hw[(size_t)s * HDIM + fo];
            acc0 += bf2f((ushort)(pk & 0xffffu));
            acc1 += bf2f((ushort)(pk >> 16));
        }
        unsigned int pk = *(const unsigned int*)&hw[(size_t)n * HDIM + fo];
        acc0 += bf2f((ushort)(pk & 0xffffu));
        acc1 += bf2f((ushort)(pk >> 16));
        float dn = dinv[n];
        acc0 = fmaf(acc0, dn, b0);
        acc1 = fmaf(acc1, dn, b1);
        *(float2*)&aggout[(size_t)n * HDIM + fo] = make_float2(acc0, acc1);
        ls0 += acc0; ls1 += acc1;
        lq0 += acc0 * acc0; lq1 += acc1 * acc1;
    }
    atomicAdd(&s_sum[fo],     ls0);
    atomicAdd(&s_sum[fo + 1], ls1);
    atomicAdd(&s_sq[fo],      lq0);
    atomicAdd(&s_sq[fo + 1],  lq1);
    __syncthreads();
    if (t < 128) { atomicAdd(&S1[t], s_sum[t]); atomicAdd(&S2[t], s_sq[t]); }
}

// ---------- 4. BN parameter prep ----------
__global__ __launch_bounds__(128)
void bn_prep(const float* __restrict__ S1, const float* __restrict__ S2,
             const float* __restrict__ gamma, const float* __restrict__ beta,
             float* __restrict__ bnp) {
    int k = threadIdx.x;
    float mean = S1[k] * (1.0f / N_NODES);
    float var  = S2[k] * (1.0f / N_NODES) - mean * mean;
    float inv  = rsqrtf(var + BN_EPS);
    float sc   = gamma[k] * inv;
    bnp[k]        = sc;
    bnp[128 + k]  = beta[k] - mean * sc;
}

// ---------- 5. mean-pool per graph with fused BN+ReLU ----------
__global__ __launch_bounds__(128)
void pool_kernel(const float* __restrict__ agg, const float* __restrict__ bnp,
                 const int* __restrict__ batch, float* __restrict__ pooled) {
    int g = blockIdx.x;
    int k = threadIdx.x;
    int lo = 0, hi = N_NODES;
    while (lo < hi) { int mid = (lo + hi) >> 1; if (batch[mid] < g) lo = mid + 1; else hi = mid; }
    int start = lo;
    hi = N_NODES;
    while (lo < hi) { int mid = (lo + hi) >> 1; if (batch[mid] < g + 1) lo = mid + 1; else hi = mid; }
    int end = lo;
    float sc = bnp[k], sh = bnp[128 + k];
    float sum = 0.f;
    for (int n = start; n < end; n++)
        sum += fmaxf(0.f, fmaf(agg[(size_t)n * HDIM + k], sc, sh));
    float cnt = (float)(end - start);
    pooled[g * HDIM + k] = sum / fmaxf(cnt, 1.0f);
}

// ---------- 6. classifier MLP ----------
__global__ __launch_bounds__(128)
void mlp_kernel(const float* __restrict__ pooled, const float* __restrict__ w1,
                const float* __restrict__ b1, const float* __restrict__ w2,
                const float* __restrict__ b2, float* __restrict__ out) {
    __shared__ float p[128];
    __shared__ float z[64];
    int g = blockIdx.x;
    int t = threadIdx.x;
    p[t] = pooled[g * HDIM + t];
    __syncthreads();
    if (t < 64) {
        float s = b1[t];
        #pragma unroll 8
        for (int k = 0; k < 128; k++) s += p[k] * w1[k * 64 + t];
        z[t] = fmaxf(0.f, s);
    }
    __syncthreads();
    if (t < NCLASS) {
        float s = b2[t];
        #pragma unroll
        for (int j = 0; j < 64; j++) s += z[j] * w2[j * NCLASS + t];
        out[g * NCLASS + t] = s;
    }
}

extern "C" void kernel_launch(void* const* d_in, const int* in_sizes, int n_in,
                              void* d_out, int out_size, void* d_ws, size_t ws_size,
                              hipStream_t stream) {
    const float* x      = (const float*)d_in[0];
    const float* conv_w = (const float*)d_in[1];
    const float* conv_b = (const float*)d_in[2];
    const float* gamma  = (const float*)d_in[3];
    const float* beta   = (const float*)d_in[4];
    const float* w1     = (const float*)d_in[5];
    const float* b1     = (const float*)d_in[6];
    const float* w2     = (const float*)d_in[7];
    const float* b2     = (const float*)d_in[8];
    const int*   ei     = (const int*)d_in[9];
    const int*   batch  = (const int*)d_in[10];
    float* out = (float*)d_out;

    char* ws = (char*)d_ws;
    size_t off = 0;
    auto alloc = [&](size_t bytes) -> void* {
        off = (off + 255) & ~(size_t)255;
        void* p = ws + off;
        off += bytes;
        return p;
    };
    ushort* A         = (ushort*)alloc((size_t)N_NODES * HDIM * 2);
    float*  B         = (float*) alloc((size_t)N_NODES * HDIM * 4);
    int*    csr_src   = (int*)   alloc((size_t)N_EDGES * 4);
    int*    row_start = (int*)   alloc((size_t)(N_NODES + 1) * 4);
    float*  dinv      = (float*) alloc((size_t)N_NODES * 4);
    int*    gcnt      = (int*)   alloc((size_t)NBUCKET * 4);
    int*    bbase     = (int*)   alloc((size_t)(NBUCKET + 1) * 4);
    int*    bcursor   = (int*)   alloc((size_t)NBUCKET * 4);
    float*  bnstats   = (float*) alloc(3 * 256 * 4);
    float*  bnp       = (float*) alloc(3 * 256 * 4);
    float*  pooled    = (float*) alloc((size_t)NGRAPH * HDIM * 4);
    // pairs aliases B: B is first written by layer-0 gather, after build_csr completes.
    unsigned int* pairs = (unsigned int*)B;

    const int* srcv = ei;
    const int* dstv = ei + N_EDGES;

    hipMemsetAsync(gcnt,    0, (size_t)NBUCKET * 4, stream);
    hipMemsetAsync(bnstats, 0, 3 * 256 * 4, stream);

    bucket_hist  <<<256, 256, 0, stream>>>(dstv, gcnt);
    bucket_scan  <<<1, 64, 0, stream>>>(gcnt, bbase, bcursor, row_start);
    scatter_pairs<<<(N_EDGES + TILE3 - 1) / TILE3, 256, 0, stream>>>(srcv, dstv, bcursor, pairs);
    build_csr    <<<NBUCKET, 256, 0, stream>>>(pairs, bbase, row_start, csr_src, dinv);

    for (int l = 0; l < 3; l++) {
        const float* inl  = (l == 0) ? x : B;
        const float* bnpl = (l == 0) ? nullptr : (bnp + (l - 1) * 256);
        gemm_bn_relu<<<N_NODES / 32, 256, 0, stream>>>(inl, conv_w + l * HDIM * HDIM, bnpl, dinv, A);
        gather_agg  <<<2048, 256, 0, stream>>>(A, row_start, csr_src, dinv,
                                               conv_b + l * HDIM, B,
                                               bnstats + l * 256, bnstats + l * 256 + 128);
        bn_prep     <<<1, 128, 0, stream>>>(bnstats + l * 256, bnstats + l * 256 + 128,
                                            gamma + l * HDIM, beta + l * HDIM, bnp + l * 256);
    }
    pool_kernel<<<NGRAPH, 128, 0, stream>>>(B, bnp + 2 * 256, batch, pooled);
    mlp_kernel <<<NGRAPH, 128, 0, stream>>>(pooled, w1, b1, w2, b2, out);
}

// Round 4
// 582.047 us; speedup vs baseline: 2.3471x; 1.3014x over previous
//
#include <hip/hip_runtime.h>
#include <hip/hip_bf16.h>

#define N_NODES 100000
#define N_EDGES 1600000
#define HDIM    128
#define NGRAPH  1000
#define NCLASS  10
#define BN_EPS  1e-5f

#define NBUCKET 391          // ceil(N_NODES / 256)
#define TILE3   8192         // edges per scatter block (196 blocks)
#define GATHER_BLOCKS 1024

typedef short short8_t __attribute__((ext_vector_type(8)));
typedef float f32x4_t  __attribute__((ext_vector_type(4)));

// ---------- bf16 helpers (manual, RNE) ----------
__device__ __forceinline__ float bf2f(ushort u) {
    union { unsigned int i; float f; } v; v.i = ((unsigned int)u) << 16; return v.f;
}
__device__ __forceinline__ ushort f2bf(float f) {
    union { float f; unsigned int i; } v; v.f = f;
    unsigned int i = v.i;
    unsigned int r = i + 0x7fffu + ((i >> 16) & 1u);
    return (ushort)(r >> 16);
}
__device__ __forceinline__ float lo16(unsigned int u) {
    union { unsigned int i; float f; } v; v.i = u << 16; return v.f;
}
__device__ __forceinline__ float hi16(unsigned int u) {
    union { unsigned int i; float f; } v; v.i = u & 0xffff0000u; return v.f;
}

// ---------- 1a. bucket histogram (bucket = dst >> 8) ----------
__global__ __launch_bounds__(256)
void bucket_hist(const int* __restrict__ dst, int* __restrict__ gcnt) {
    __shared__ int h[NBUCKET];
    int t = threadIdx.x;
    for (int i = t; i < NBUCKET; i += 256) h[i] = 0;
    __syncthreads();
    int i0 = blockIdx.x * blockDim.x + t;
    int stride = gridDim.x * blockDim.x;
    for (int e = i0; e < N_EDGES; e += stride)
        atomicAdd(&h[dst[e] >> 8], 1);
    __syncthreads();
    for (int i = t; i < NBUCKET; i += 256)
        if (h[i]) atomicAdd(&gcnt[i], h[i]);
}

// ---------- 1b. bucket scan ----------
__global__ void bucket_scan(const int* __restrict__ gcnt, int* __restrict__ bucket_base,
                            int* __restrict__ bucket_cursor, int* __restrict__ row_start) {
    if (threadIdx.x == 0) {
        int s = 0;
        for (int i = 0; i < NBUCKET; i++) {
            bucket_base[i] = s;
            bucket_cursor[i] = s;
            s += gcnt[i];
        }
        bucket_base[NBUCKET] = s;
        row_start[N_NODES] = N_EDGES;
    }
}

// ---------- 1c. tile-local scatter of packed (src | local<<24) ----------
__global__ __launch_bounds__(256)
void scatter_pairs(const int* __restrict__ src, const int* __restrict__ dst,
                   int* __restrict__ bucket_cursor, unsigned int* __restrict__ pairs) {
    __shared__ int lhist[NBUCKET];
    __shared__ int lbase[NBUCKET];
    __shared__ int lcur[NBUCKET];
    int t = threadIdx.x;
    long tile0 = (long)blockIdx.x * TILE3;
    for (int i = t; i < NBUCKET; i += 256) { lhist[i] = 0; lcur[i] = 0; }
    __syncthreads();
    #pragma unroll 4
    for (int i = 0; i < TILE3 / 256; i++) {
        long e = tile0 + t + i * 256;
        if (e < N_EDGES) atomicAdd(&lhist[dst[e] >> 8], 1);
    }
    __syncthreads();
    for (int i = t; i < NBUCKET; i += 256)
        if (lhist[i] > 0) lbase[i] = atomicAdd(&bucket_cursor[i], lhist[i]);
    __syncthreads();
    #pragma unroll 4
    for (int i = 0; i < TILE3 / 256; i++) {
        long e = tile0 + t + i * 256;
        if (e < N_EDGES) {
            int d = dst[e];
            int bkt = d >> 8;
            int p = atomicAdd(&lcur[bkt], 1);
            pairs[lbase[bkt] + p] = (unsigned int)src[e] | ((unsigned int)(d & 255) << 24);
        }
    }
}

// ---------- 1d. per-bucket CSR build ----------
__global__ __launch_bounds__(256)
void build_csr(const unsigned int* __restrict__ pairs, const int* __restrict__ bucket_base,
               int* __restrict__ row_start, int* __restrict__ csr_src, float* __restrict__ dinv) {
    __shared__ int hist[256];
    __shared__ int cur[256];
    __shared__ int wsum[4];
    int b = blockIdx.x;
    int t = threadIdx.x;
    int beg = bucket_base[b], end = bucket_base[b + 1];
    hist[t] = 0;
    __syncthreads();
    for (int e = beg + t; e < end; e += 256)
        atomicAdd(&hist[pairs[e] >> 24], 1);
    __syncthreads();
    int v = hist[t];
    int lane = t & 63, wid = t >> 6;
    int x = v;
    #pragma unroll
    for (int off = 1; off < 64; off <<= 1) {
        int y = __shfl_up(x, off, 64);
        if (lane >= off) x += y;
    }
    if (lane == 63) wsum[wid] = x;
    __syncthreads();
    if (t == 0) {
        int s = 0;
        #pragma unroll
        for (int w = 0; w < 4; w++) { int tmp = wsum[w]; wsum[w] = s; s += tmp; }
    }
    __syncthreads();
    int excl = wsum[wid] + (x - v);
    cur[t] = excl;
    int node = b * 256 + t;
    if (node < N_NODES) {
        row_start[node] = beg + excl;
        dinv[node] = rsqrtf(1.0f + (float)v);
    }
    __syncthreads();
    for (int e = beg + t; e < end; e += 256) {
        unsigned int pk = pairs[e];
        int ln = pk >> 24;
        int sp = atomicAdd(&cur[ln], 1);
        csr_src[beg + sp] = (int)(pk & 0xFFFFFFu);
    }
}

// ---------- 2a. W^T prep: wtbT[l][n][k] = bf16(conv_w[l][k][n]) ----------
__global__ __launch_bounds__(256)
void conv_w_prep(const float* __restrict__ W, ushort* __restrict__ wtbT) {
    int l = blockIdx.x >> 4, slice = blockIdx.x & 15;
    int t = threadIdx.x;
    int idx = slice * 1024 + t * 4;        // 4 consecutive along n
    int k = idx >> 7, n = idx & 127;
    float4 w4 = *(const float4*)&W[(size_t)l * 16384 + k * 128 + n];
    ushort* o = wtbT + (size_t)l * 16384;
    o[(n + 0) * 128 + k] = f2bf(w4.x);
    o[(n + 1) * 128 + k] = f2bf(w4.y);
    o[(n + 2) * 128 + k] = f2bf(w4.z);
    o[(n + 3) * 128 + k] = f2bf(w4.w);
}

// ---------- 2b. MFMA GEMM: out = bf16(dinv * (f(in) @ W)), f = BN+ReLU or identity ----------
// 64 rows/block, 4 waves, each wave 16 rows x 128 cols via 8x4 mfma_f32_16x16x32_bf16.
// A-frag: lane m=c, k=g*8+j from as_[m][k]; B-frag: lane n=c, k=g*8+j from wt[n][k] (W^T).
// D: col = ct*16+c, row = g*4+reg (m97-verified mapping).
__global__ __launch_bounds__(256)
void gemm_mfma(const float* __restrict__ in, const ushort* __restrict__ wtbT,
               const float* __restrict__ bnp, const float* __restrict__ dinv,
               ushort* __restrict__ out) {
    __shared__ ushort as_[64][136];   // +8 pad: rows stride 272B = 17x16B, bank-rotates
    __shared__ ushort wt[128][136];
    int t = threadIdx.x;
    int wave = t >> 6, lane = t & 63;
    int g = lane >> 4, c = lane & 15;
    int rowbase = blockIdx.x * 64;

    // stage W^T (16384 ushorts as 2048 x 16B)
    #pragma unroll
    for (int i = 0; i < 8; i++) {
        int cid = t + i * 256;
        int n = cid >> 4, ko = (cid & 15) * 8;
        uint4 v = *(const uint4*)&wtbT[n * 128 + ko];
        *(uint4*)&wt[n][ko] = v;
    }
    // stage A tile with fused BN+ReLU, fp32 -> bf16
    #pragma unroll
    for (int i = 0; i < 8; i++) {
        int cid = t + i * 256;
        int r = cid >> 5, co = (cid & 31) * 4;
        int row = rowbase + r;
        ushort4 pk = make_ushort4(0, 0, 0, 0);
        if (row < N_NODES) {
            float4 v = *(const float4*)&in[(size_t)row * HDIM + co];
            if (bnp != nullptr) {
                float4 sc = *(const float4*)&bnp[co];
                float4 sh = *(const float4*)&bnp[128 + co];
                v.x = fmaxf(0.f, fmaf(v.x, sc.x, sh.x));
                v.y = fmaxf(0.f, fmaf(v.y, sc.y, sh.y));
                v.z = fmaxf(0.f, fmaf(v.z, sc.z, sh.z));
                v.w = fmaxf(0.f, fmaf(v.w, sc.w, sh.w));
            }
            pk.x = f2bf(v.x); pk.y = f2bf(v.y); pk.z = f2bf(v.z); pk.w = f2bf(v.w);
        }
        *(ushort4*)&as_[r][co] = pk;
    }
    __syncthreads();

    int m0 = wave * 16;
    short8_t a[4];
    #pragma unroll
    for (int ch = 0; ch < 4; ch++)
        a[ch] = *(const short8_t*)&as_[m0 + c][ch * 32 + g * 8];
    f32x4_t acc[8] = {};
    #pragma unroll
    for (int ct = 0; ct < 8; ct++) {
        #pragma unroll
        for (int ch = 0; ch < 4; ch++) {
            short8_t b = *(const short8_t*)&wt[ct * 16 + c][ch * 32 + g * 8];
            acc[ct] = __builtin_amdgcn_mfma_f32_16x16x32_bf16(a[ch], b, acc[ct], 0, 0, 0);
        }
    }
    float dv[4];
    #pragma unroll
    for (int reg = 0; reg < 4; reg++) {
        int rr = rowbase + m0 + g * 4 + reg;
        dv[reg] = dinv[rr < N_NODES ? rr : 0];
    }
    __syncthreads();
    // deposit D (bf16, dinv-scaled) into as_ for coalesced store
    #pragma unroll
    for (int ct = 0; ct < 8; ct++)
        #pragma unroll
        for (int reg = 0; reg < 4; reg++)
            as_[m0 + g * 4 + reg][ct * 16 + c] = f2bf(acc[ct][reg] * dv[reg]);
    __syncthreads();
    #pragma unroll
    for (int i = 0; i < 8; i++) {
        int cid = t + i * 256;
        int r = cid >> 5, co = (cid & 31) * 4;
        int row = rowbase + r;
        if (row < N_NODES)
            *(ushort4*)&out[(size_t)row * HDIM + co] = *(const ushort4*)&as_[r][co];
    }
}

// ---------- 3. gather: agg[n] = dinv[n]*(sum_e A'[s] + A'[n]) + b ----------
// one wave per node; subgroup g=lane>>4 handles edge j+g, lane c=lane&15 loads 16B (8 features).
// shfl_xor(16/32) butterfly combines subgroups; BN stats -> per-block partials (no global atomics).
__global__ __launch_bounds__(256)
void gather_agg(const ushort* __restrict__ hw, const int* __restrict__ row_start,
                const int* __restrict__ csr_src, const float* __restrict__ dinv,
                const float* __restrict__ bias, float* __restrict__ aggout,
                float* __restrict__ Spart, float* __restrict__ Qpart) {
    __shared__ float s_sum[128];
    __shared__ float s_sq[128];
    int t = threadIdx.x;
    if (t < 128) { s_sum[t] = 0.f; s_sq[t] = 0.f; }
    __syncthreads();
    int lane = t & 63, wid = t >> 6;
    int g = lane >> 4, c = lane & 15;
    int fo = c * 8;
    float4 bA = *(const float4*)&bias[fo];
    float4 bB = *(const float4*)&bias[fo + 4];
    float ls[8] = {}, lq[8] = {};
    int gw = blockIdx.x * 4 + wid;
    int nw = gridDim.x * 4;
    for (int n = gw; n < N_NODES; n += nw) {
        int jb = row_start[n], je = row_start[n + 1];
        float acc[8] = {};
        int j = jb;
        for (; j + 8 <= je; j += 8) {
            int sa = csr_src[j + 2 * g];
            int sb = csr_src[j + 2 * g + 1];
            uint4 p = *(const uint4*)&hw[(size_t)sa * HDIM + fo];
            uint4 q = *(const uint4*)&hw[(size_t)sb * HDIM + fo];
            acc[0] += lo16(p.x) + lo16(q.x);
            acc[1] += hi16(p.x) + hi16(q.x);
            acc[2] += lo16(p.y) + lo16(q.y);
            acc[3] += hi16(p.y) + hi16(q.y);
            acc[4] += lo16(p.z) + lo16(q.z);
            acc[5] += hi16(p.z) + hi16(q.z);
            acc[6] += lo16(p.w) + lo16(q.w);
            acc[7] += hi16(p.w) + hi16(q.w);
        }
        int e0 = j + g, e1 = j + 4 + g;
        if (e0 < je) {
            int s = csr_src[e0];
            uint4 p = *(const uint4*)&hw[(size_t)s * HDIM + fo];
            acc[0] += lo16(p.x); acc[1] += hi16(p.x);
            acc[2] += lo16(p.y); acc[3] += hi16(p.y);
            acc[4] += lo16(p.z); acc[5] += hi16(p.z);
            acc[6] += lo16(p.w); acc[7] += hi16(p.w);
        }
        if (e1 < je) {
            int s = csr_src[e1];
            uint4 p = *(const uint4*)&hw[(size_t)s * HDIM + fo];
            acc[0] += lo16(p.x); acc[1] += hi16(p.x);
            acc[2] += lo16(p.y); acc[3] += hi16(p.y);
            acc[4] += lo16(p.z); acc[5] += hi16(p.z);
            acc[6] += lo16(p.w); acc[7] += hi16(p.w);
        }
        #pragma unroll
        for (int i = 0; i < 8; i++) {
            acc[i] += __shfl_xor(acc[i], 16);
            acc[i] += __shfl_xor(acc[i], 32);
        }
        // self-loop (A' rows already dinv-scaled), then *dinv[n] + bias
        uint4 ps = *(const uint4*)&hw[(size_t)n * HDIM + fo];
        float dn = dinv[n];
        float r[8];
        r[0] = fmaf(acc[0] + lo16(ps.x), dn, bA.x);
        r[1] = fmaf(acc[1] + hi16(ps.x), dn, bA.y);
        r[2] = fmaf(acc[2] + lo16(ps.y), dn, bA.z);
        r[3] = fmaf(acc[3] + hi16(ps.y), dn, bA.w);
        r[4] = fmaf(acc[4] + lo16(ps.z), dn, bB.x);
        r[5] = fmaf(acc[5] + hi16(ps.z), dn, bB.y);
        r[6] = fmaf(acc[6] + lo16(ps.w), dn, bB.z);
        r[7] = fmaf(acc[7] + hi16(ps.w), dn, bB.w);
        if (g == 0) {
            *(float4*)&aggout[(size_t)n * HDIM + fo]     = make_float4(r[0], r[1], r[2], r[3]);
            *(float4*)&aggout[(size_t)n * HDIM + fo + 4] = make_float4(r[4], r[5], r[6], r[7]);
            #pragma unroll
            for (int i = 0; i < 8; i++) { ls[i] += r[i]; lq[i] += r[i] * r[i]; }
        }
    }
    if (g == 0) {
        #pragma unroll
        for (int i = 0; i < 8; i++) {
            atomicAdd(&s_sum[fo + i], ls[i]);
            atomicAdd(&s_sq[fo + i],  lq[i]);
        }
    }
    __syncthreads();
    if (t < 128) {
        Spart[(size_t)blockIdx.x * 128 + t] = s_sum[t];
        Qpart[(size_t)blockIdx.x * 128 + t] = s_sq[t];
    }
}

// ---------- 4. BN reduce + prep: 16 blocks x 8 features ----------
__global__ __launch_bounds__(256)
void bn_reduce_prep(const float* __restrict__ Spart, const float* __restrict__ Qpart,
                    const float* __restrict__ gamma, const float* __restrict__ beta,
                    float* __restrict__ bnp) {
    __shared__ float rs[32][8];
    __shared__ float rq[32][8];
    int t = threadIdx.x;
    int fi = t & 7, chunk = t >> 3;
    int f = blockIdx.x * 8 + fi;
    float s = 0.f, q = 0.f;
    for (int b = chunk; b < GATHER_BLOCKS; b += 32) {
        s += Spart[(size_t)b * 128 + f];
        q += Qpart[(size_t)b * 128 + f];
    }
    rs[chunk][fi] = s; rq[chunk][fi] = q;
    __syncthreads();
    if (t < 8) {
        float S = 0.f, Q = 0.f;
        #pragma unroll
        for (int cc = 0; cc < 32; cc++) { S += rs[cc][t]; Q += rq[cc][t]; }
        int ff = blockIdx.x * 8 + t;
        float mean = S * (1.0f / N_NODES);
        float var  = Q * (1.0f / N_NODES) - mean * mean;
        float inv  = rsqrtf(var + BN_EPS);
        float sc   = gamma[ff] * inv;
        bnp[ff]       = sc;
        bnp[128 + ff] = beta[ff] - mean * sc;
    }
}

// ---------- 5. mean-pool per graph with fused BN+ReLU ----------
__global__ __launch_bounds__(128)
void pool_kernel(const float* __restrict__ agg, const float* __restrict__ bnp,
                 const int* __restrict__ batch, float* __restrict__ pooled) {
    int g = blockIdx.x;
    int k = threadIdx.x;
    int lo = 0, hi = N_NODES;
    while (lo < hi) { int mid = (lo + hi) >> 1; if (batch[mid] < g) lo = mid + 1; else hi = mid; }
    int start = lo;
    hi = N_NODES;
    while (lo < hi) { int mid = (lo + hi) >> 1; if (batch[mid] < g + 1) lo = mid + 1; else hi = mid; }
    int end = lo;
    float sc = bnp[k], sh = bnp[128 + k];
    float sum = 0.f;
    for (int n = start; n < end; n++)
        sum += fmaxf(0.f, fmaf(agg[(size_t)n * HDIM + k], sc, sh));
    float cnt = (float)(end - start);
    pooled[g * HDIM + k] = sum / fmaxf(cnt, 1.0f);
}

// ---------- 6. classifier MLP ----------
__global__ __launch_bounds__(128)
void mlp_kernel(const float* __restrict__ pooled, const float* __restrict__ w1,
                const float* __restrict__ b1, const float* __restrict__ w2,
                const float* __restrict__ b2, float* __restrict__ out) {
    __shared__ float p[128];
    __shared__ float z[64];
    int g = blockIdx.x;
    int t = threadIdx.x;
    p[t] = pooled[g * HDIM + t];
    __syncthreads();
    if (t < 64) {
        float s = b1[t];
        #pragma unroll 8
        for (int k = 0; k < 128; k++) s += p[k] * w1[k * 64 + t];
        z[t] = fmaxf(0.f, s);
    }
    __syncthreads();
    if (t < NCLASS) {
        float s = b2[t];
        #pragma unroll
        for (int j = 0; j < 64; j++) s += z[j] * w2[j * NCLASS + t];
        out[g * NCLASS + t] = s;
    }
}

extern "C" void kernel_launch(void* const* d_in, const int* in_sizes, int n_in,
                              void* d_out, int out_size, void* d_ws, size_t ws_size,
                              hipStream_t stream) {
    const float* x      = (const float*)d_in[0];
    const float* conv_w = (const float*)d_in[1];
    const float* conv_b = (const float*)d_in[2];
    const float* gamma  = (const float*)d_in[3];
    const float* beta   = (const float*)d_in[4];
    const float* w1     = (const float*)d_in[5];
    const float* b1     = (const float*)d_in[6];
    const float* w2     = (const float*)d_in[7];
    const float* b2     = (const float*)d_in[8];
    const int*   ei     = (const int*)d_in[9];
    const int*   batch  = (const int*)d_in[10];
    float* out = (float*)d_out;

    char* ws = (char*)d_ws;
    size_t off = 0;
    auto alloc = [&](size_t bytes) -> void* {
        off = (off + 255) & ~(size_t)255;
        void* p = ws + off;
        off += bytes;
        return p;
    };
    ushort* A         = (ushort*)alloc((size_t)N_NODES * HDIM * 2);
    float*  B         = (float*) alloc((size_t)N_NODES * HDIM * 4);
    int*    csr_src   = (int*)   alloc((size_t)N_EDGES * 4);
    int*    row_start = (int*)   alloc((size_t)(N_NODES + 1) * 4);
    float*  dinv      = (float*) alloc((size_t)N_NODES * 4);
    int*    gcnt      = (int*)   alloc((size_t)NBUCKET * 4);
    int*    bbase     = (int*)   alloc((size_t)(NBUCKET + 1) * 4);
    int*    bcursor   = (int*)   alloc((size_t)NBUCKET * 4);
    ushort* wtbT      = (ushort*)alloc((size_t)3 * 16384 * 2);
    float*  Spart     = (float*) alloc((size_t)GATHER_BLOCKS * 128 * 4);
    float*  Qpart     = (float*) alloc((size_t)GATHER_BLOCKS * 128 * 4);
    float*  bnp       = (float*) alloc(3 * 256 * 4);
    float*  pooled    = (float*) alloc((size_t)NGRAPH * HDIM * 4);
    // pairs aliases B: B is first written by layer-0 gather, after build_csr completes.
    unsigned int* pairs = (unsigned int*)B;

    const int* srcv = ei;
    const int* dstv = ei + N_EDGES;

    hipMemsetAsync(gcnt, 0, (size_t)NBUCKET * 4, stream);

    bucket_hist  <<<256, 256, 0, stream>>>(dstv, gcnt);
    bucket_scan  <<<1, 64, 0, stream>>>(gcnt, bbase, bcursor, row_start);
    scatter_pairs<<<(N_EDGES + TILE3 - 1) / TILE3, 256, 0, stream>>>(srcv, dstv, bcursor, pairs);
    build_csr    <<<NBUCKET, 256, 0, stream>>>(pairs, bbase, row_start, csr_src, dinv);
    conv_w_prep  <<<48, 256, 0, stream>>>(conv_w, wtbT);

    for (int l = 0; l < 3; l++) {
        const float* inl  = (l == 0) ? x : B;
        const float* bnpl = (l == 0) ? nullptr : (bnp + (l - 1) * 256);
        gemm_mfma<<<(N_NODES + 63) / 64, 256, 0, stream>>>(inl, wtbT + (size_t)l * 16384,
                                                           bnpl, dinv, A);
        gather_agg<<<GATHER_BLOCKS, 256, 0, stream>>>(A, row_start, csr_src, dinv,
                                                      conv_b + l * HDIM, B, Spart, Qpart);
        bn_reduce_prep<<<16, 256, 0, stream>>>(Spart, Qpart, gamma + l * HDIM,
                                               beta + l * HDIM, bnp + l * 256);
    }
    pool_kernel<<<NGRAPH, 128, 0, stream>>>(B, bnp + 2 * 256, batch, pooled);
    mlp_kernel <<<NGRAPH, 128, 0, stream>>>(pooled, w1, b1, w2, b2, out);
}